// Round 5
// baseline (662.369 us; speedup 1.0000x reference)
//
#include <hip/hip_runtime.h>
#include <math.h>

// ---------------- problem constants ----------------
#define BB_ 64
#define P_  24
#define C_  40
#define WIN_ 64
#define L1_ 60
#define L2_ 56
#define R_  1344

// ---------------- ws layout (float offsets) ----------------
#define O_USQ   0ull
#define O_UHAT  2752512ull
#define O_H     2752512ull          // alias (dead before k6 writes uhat)
#define O_PART  3735552ull          // 4 * 2752512 floats of conv2 K-split partials
#define O_UP    14745600ull
#define O_STATS 57802752ull
#define O_A1    57803328ull
#define O_B1S   57803584ull
#define O_A2    57803840ull
#define O_B2S   57803872ull
#define O_S     57803904ull         // s0,s1,s2,vsum each 40960
#define O_V     57967744ull
#define WS_FLOATS_NEEDED 58008704ull

__device__ __forceinline__ float dot4f(float4 a, float4 b) {
    return a.x*b.x + a.y*b.y + a.z*b.z + a.w*b.w;
}

// ============ K1: conv1 (24->256, k=5) + bias, h layout (b, l, o) ============
__global__ void k1_conv1(const float* __restrict__ x, const float* __restrict__ w1,
                         const float* __restrict__ c1b, float* __restrict__ h) {
    __shared__ float xs[24 * 20];
    __shared__ float wl[64 * 121];
    int t = threadIdx.x;
    int lq = blockIdx.x, b = blockIdx.y, ocg = blockIdx.z;
    for (int idx = t; idx < 456; idx += 256) {
        int p = idx / 19, tau = idx - p * 19;
        xs[p * 20 + tau] = x[b * 1536 + (lq * 15 + tau) * 24 + p];
    }
    for (int idx = t; idx < 7680; idx += 256) {
        int o_ = idx / 120, cix = idx - o_ * 120;
        wl[o_ * 121 + cix] = w1[(ocg * 64 + o_) * 120 + cix];
    }
    __syncthreads();
    int g = t >> 6;
    int ol = t & 63;
    int LV = (g < 3) ? 4 : 3;
    int o = ocg * 64 + ol;
    float acc[4] = {0.f, 0.f, 0.f, 0.f};
    for (int p = 0; p < 24; p++) {
        float4 xa = *(const float4*)&xs[p * 20 + g * 4];
        float4 xb = *(const float4*)&xs[p * 20 + g * 4 + 4];
        float xr[8] = {xa.x, xa.y, xa.z, xa.w, xb.x, xb.y, xb.z, xb.w};
        #pragma unroll
        for (int k = 0; k < 5; k++) {
            float w = wl[ol * 121 + p * 5 + k];
            #pragma unroll
            for (int li = 0; li < 4; li++) acc[li] += xr[li + k] * w;
        }
    }
    for (int li = 0; li < LV; li++) {
        int l = lq * 15 + g * 4 + li;
        h[(size_t)(b * 60 + l) * 256 + o] = acc[li] + c1b[o];
    }
}

// ============ K2a: BN1 stats ============
__global__ void k2a(const float* __restrict__ h, float* __restrict__ sum1, float* __restrict__ ss1) {
    int t = threadIdx.x;
    float s = 0.f, q = 0.f;
    for (int i = 0; i < 64; i++) {
        float v = h[(size_t)(blockIdx.x * 64 + i) * 256 + t];
        s += v; q += v * v;
    }
    atomicAdd(&sum1[t], s);
    atomicAdd(&ss1[t], q);
}

__global__ void k2b(const float* __restrict__ sum1, const float* __restrict__ ss1,
                    const float* __restrict__ g, const float* __restrict__ be,
                    float* __restrict__ a1, float* __restrict__ b1s) {
    int o = threadIdx.x;
    float m = sum1[o] * (1.f / 3840.f);
    float v = ss1[o] * (1.f / 3840.f) - m * m;
    float a = g[o] / sqrtf(v + 1e-5f);
    a1[o] = a;
    b1s[o] = be[o] - m * a;
}

// ============ K3: primary conv (256->768, k=5), K-split x4, 8-ic chunks ============
// LDS: hs 488 + wl 40x133 = 23.2 KB -> 6 blocks/CU (was 46.6 KB -> 3).
__global__ __launch_bounds__(128) void k3_conv2(
        const float* __restrict__ h, const float* __restrict__ a1, const float* __restrict__ b1s,
        const float* __restrict__ w2, float* __restrict__ part) {
    __shared__ float hs[488];        // 8 ic x 60 l (+8 overread pad)
    __shared__ float wl[5320];       // (8 ic * 5 k) rows x 128 o2, stride 133
    int t = threadIdx.x;
    int tile = blockIdx.x, b = blockIdx.y, ks = blockIdx.z;
    int lane = t & 63, wv_ = t >> 6;
    int og = lane >> 3, lg = lane & 7;
    int o2b = tile * 128 + wv_ * 64 + og * 8;
    float acc[8][8];
    #pragma unroll
    for (int i = 0; i < 8; i++)
        #pragma unroll
        for (int j = 0; j < 8; j++) acc[i][j] = 0.f;

    int oc0 = ks * 64;
    for (int oc = oc0; oc < oc0 + 64; oc += 8) {
        __syncthreads();
        for (int idx = t; idx < 480; idx += 128) {
            int o_ = idx & 7, l = idx >> 3;
            float v = h[(size_t)(b * 60 + l) * 256 + oc + o_];
            hs[o_ * 60 + l] = fmaxf(a1[oc + o_] * v + b1s[oc + o_], 0.f);
        }
        for (int idx = t; idx < 5120; idx += 128) {
            int o2l = idx / 40, rest = idx - o2l * 40;   // rest = ic'*5 + k
            wl[rest * 133 + o2l] = w2[(size_t)(tile * 128 + o2l) * 1280 + oc * 5 + rest];
        }
        __syncthreads();
        for (int o_ = 0; o_ < 8; o_++) {
            const float4* h4 = (const float4*)&hs[o_ * 60];
            float4 ha = h4[lg * 2], hb = h4[lg * 2 + 1], hc = h4[lg * 2 + 2];
            float hw[12] = {ha.x, ha.y, ha.z, ha.w, hb.x, hb.y, hb.z, hb.w, hc.x, hc.y, hc.z, hc.w};
            #pragma unroll
            for (int k = 0; k < 5; k++) {
                const float4* w4 = (const float4*)&wl[(o_ * 5 + k) * 133];
                float4 wa = w4[wv_ * 16 + og * 2];
                float4 wb = w4[wv_ * 16 + og * 2 + 1];
                float wr[8] = {wa.x, wa.y, wa.z, wa.w, wb.x, wb.y, wb.z, wb.w};
                #pragma unroll
                for (int li = 0; li < 8; li++)
                    #pragma unroll
                    for (int oi = 0; oi < 8; oi++)
                        acc[li][oi] += hw[li + k] * wr[oi];
            }
        }
    }
    if (lg < 7) {
        float* dst = part + (size_t)ks * 2752512;
        #pragma unroll
        for (int li = 0; li < 8; li++) {
            int l = lg * 8 + li;
            size_t base = (size_t)b * 43008 + (size_t)l * 768 + o2b;
            float4 v0 = {acc[li][0], acc[li][1], acc[li][2], acc[li][3]};
            float4 v1 = {acc[li][4], acc[li][5], acc[li][6], acc[li][7]};
            *(float4*)&dst[base] = v0;
            *(float4*)&dst[base + 4] = v1;
        }
    }
}

// ============ K4r: reduce K-split partials + bias -> up, and BN2 stats ============
__global__ void k4r(const float* __restrict__ part, const float* __restrict__ pb,
                    float* __restrict__ up, float* __restrict__ sum2, float* __restrict__ ss2) {
    __shared__ float rs[256], rq[256];
    int t = threadIdx.x;
    float s = 0.f, q = 0.f;
    for (int i = 0; i < 32; i++) {
        size_t row = (size_t)(blockIdx.x * 32 + i) * 768;
        for (int c0 = 0; c0 < 768; c0 += 256) {
            int idx = c0 + t;
            float v = part[row + idx] + part[2752512ull + row + idx]
                    + part[2ull * 2752512ull + row + idx] + part[3ull * 2752512ull + row + idx]
                    + pb[idx];
            up[row + idx] = v;
            s += v; q += v * v;
        }
    }
    rs[t] = s; rq[t] = q;
    __syncthreads();
    if (t < 32) {
        float S = 0.f, Q = 0.f;
        for (int g2 = 0; g2 < 8; g2++) { S += rs[t + 32 * g2]; Q += rq[t + 32 * g2]; }
        atomicAdd(&sum2[t], S);
        atomicAdd(&ss2[t], Q);
    }
}

__global__ void k4b(const float* __restrict__ sum2, const float* __restrict__ ss2,
                    const float* __restrict__ g, const float* __restrict__ be,
                    float* __restrict__ a2, float* __restrict__ b2s) {
    int j = threadIdx.x;
    if (j >= 32) return;
    float m = sum2[j] * (1.f / 86016.f);
    float v = ss2[j] * (1.f / 86016.f) - m * m;
    float a = g[j] / sqrtf(v + 1e-5f);
    a2[j] = a;
    b2s[j] = be[j] - m * a;
}

// ============ K5: BN2 apply + squash over 32 -> usq (b, r, i) ============
__global__ void k5(const float* __restrict__ up, const float* __restrict__ a2,
                   const float* __restrict__ b2s, float* __restrict__ usq) {
    int t = threadIdx.x;
    int row = blockIdx.x * 8 + (t >> 5);
    int j = t & 31;
    int b = row / 1344, r = row - b * 1344;
    int p = r / 56, l = r - p * 56;
    float v = up[(size_t)b * 43008 + (size_t)l * 768 + p * 32 + j];
    float xv = a2[j] * v + b2s[j];
    float sq = xv * xv;
    #pragma unroll
    for (int m = 16; m >= 1; m >>= 1) sq += __shfl_xor(sq, m, 32);
    float scale = (sq / (1.f + sq)) / (sqrtf(sq) + 1e-8f);
    usq[(size_t)row * 32 + j] = xv * scale;
}

// ============ K6: batched GEMM per r: uhat[b, cd] = U[b,i] . W[cd,i] ============
__global__ __launch_bounds__(256) void k6_uhat(const float* __restrict__ usq,
                                               const float* __restrict__ W,
                                               float* __restrict__ uh) {
    __shared__ float us[64 * 36];
    __shared__ float wl[128 * 36];
    int t = threadIdx.x;
    int cdt = blockIdx.x, r = blockIdx.y;

    #pragma unroll
    for (int q = 0; q < 2; q++) {
        int idx4 = q * 256 + t;
        int b = idx4 >> 3, i4 = idx4 & 7;
        float4 v = *(const float4*)&usq[(size_t)(b * 1344 + r) * 32 + i4 * 4];
        *(float4*)&us[b * 36 + i4 * 4] = v;
    }
    #pragma unroll
    for (int q = 0; q < 4; q++) {
        int idx4 = q * 256 + t;
        int c_l = idx4 >> 7;
        int rest4 = idx4 & 127;
        float4 v = *(const float4*)&W[(size_t)(cdt * 8 + c_l) * 688128ull +
                                      (size_t)r * 512 + rest4 * 4];
        int cd_l = c_l * 16 + (rest4 >> 3);
        int i4 = rest4 & 7;
        *(float4*)&wl[cd_l * 36 + i4 * 4] = v;
    }
    __syncthreads();

    int tb = t & 7, tcd = t >> 3;
    float acc[8][4];
    #pragma unroll
    for (int i = 0; i < 8; i++)
        #pragma unroll
        for (int j = 0; j < 4; j++) acc[i][j] = 0.f;

    #pragma unroll
    for (int k4 = 0; k4 < 8; k4++) {
        float4 wv[4], ub[8];
        #pragma unroll
        for (int j = 0; j < 4; j++)
            wv[j] = *(const float4*)&wl[(tcd * 4 + j) * 36 + k4 * 4];
        #pragma unroll
        for (int bj = 0; bj < 8; bj++)
            ub[bj] = *(const float4*)&us[(bj * 8 + tb) * 36 + k4 * 4];
        #pragma unroll
        for (int bj = 0; bj < 8; bj++)
            #pragma unroll
            for (int j = 0; j < 4; j++)
                acc[bj][j] += dot4f(ub[bj], wv[j]);
    }

    #pragma unroll
    for (int bj = 0; bj < 8; bj++) {
        int b = bj * 8 + tb;
        float4 o = {acc[bj][0], acc[bj][1], acc[bj][2], acc[bj][3]};
        *(float4*)&uh[(size_t)(b * 1344 + r) * 640 + cdt * 128 + tcd * 4] = o;
    }
}

// ============ K_route: 8 r per wave, grid (42, 64) ============
template<int UNIFORM>
__global__ void k_route(const float* __restrict__ uh, const float* __restrict__ vsum,
                        float* __restrict__ sout) {
    __shared__ float sl[2560];
    int t = threadIdx.x, wid = t >> 6, lane = t & 63;
    int b = blockIdx.y, rt = blockIdx.x;
    bool act = lane < 40;
    int c = act ? lane : 0;
    float4 vs0 = {0,0,0,0}, vs1 = vs0, vs2 = vs0, vs3 = vs0;
    if (UNIFORM == 0 && act) {
        const float4* vp = (const float4*)&vsum[b * 640 + c * 16];
        vs0 = vp[0]; vs1 = vp[1]; vs2 = vp[2]; vs3 = vp[3];
    }
    float4 ac0 = {0,0,0,0}, ac1 = ac0, ac2 = ac0, ac3 = ac0;
    for (int i = 0; i < 8; i++) {
        int r = rt * 32 + wid * 8 + i;
        const float4* u4 = (const float4*)&uh[((size_t)(b * 1344 + r) * 40 + c) * 16];
        float4 a0 = {0,0,0,0}, a1 = a0, a2 = a0, a3 = a0;
        if (act) { a0 = u4[0]; a1 = u4[1]; a2 = u4[2]; a3 = u4[3]; }
        float w;
        if (UNIFORM) {
            w = 0.025f;
        } else {
            float dt = act ? (dot4f(a0, vs0) + dot4f(a1, vs1) + dot4f(a2, vs2) + dot4f(a3, vs3))
                           : -1e30f;
            float mx = dt;
            #pragma unroll
            for (int m2 = 32; m2 >= 1; m2 >>= 1) mx = fmaxf(mx, __shfl_xor(mx, m2));
            float e = act ? __expf(dt - mx) : 0.f;
            float se = e;
            #pragma unroll
            for (int m2 = 32; m2 >= 1; m2 >>= 1) se += __shfl_xor(se, m2);
            w = e / se;
        }
        ac0.x += w * a0.x; ac0.y += w * a0.y; ac0.z += w * a0.z; ac0.w += w * a0.w;
        ac1.x += w * a1.x; ac1.y += w * a1.y; ac1.z += w * a1.z; ac1.w += w * a1.w;
        ac2.x += w * a2.x; ac2.y += w * a2.y; ac2.z += w * a2.z; ac2.w += w * a2.w;
        ac3.x += w * a3.x; ac3.y += w * a3.y; ac3.z += w * a3.z; ac3.w += w * a3.w;
    }
    if (act) {
        float4* sp = (float4*)&sl[wid * 640 + c * 16];
        sp[0] = ac0; sp[1] = ac1; sp[2] = ac2; sp[3] = ac3;
    }
    __syncthreads();
    for (int jj = t; jj < 640; jj += 256)
        atomicAdd(&sout[b * 640 + jj], sl[jj] + sl[640 + jj] + sl[1280 + jj] + sl[1920 + jj]);
}

// ============ K8: squash s -> v ============
__global__ void k8(const float* __restrict__ sin, float* __restrict__ vout,
                   float* __restrict__ vsum, int addsum) {
    int t = threadIdx.x;
    int row = blockIdx.x * 16 + (t >> 4);
    int d = t & 15;
    float v = sin[row * 16 + d];
    float sq = v * v;
    #pragma unroll
    for (int m = 8; m >= 1; m >>= 1) sq += __shfl_xor(sq, m, 16);
    float scale = (sq / (1.f + sq)) / (sqrtf(sq) + 1e-8f);
    float o = v * scale;
    vout[row * 16 + d] = o;
    if (addsum) vsum[row * 16 + d] += o;
}

// ============ K10: head (512 thr) ============
__global__ void k10_head(const float* __restrict__ v,
                         const float* __restrict__ cw1, const float* __restrict__ cb1,
                         const float* __restrict__ cw2, const float* __restrict__ cb2,
                         const float* __restrict__ dw1, const float* __restrict__ db1,
                         const float* __restrict__ dw2, const float* __restrict__ db2,
                         float* __restrict__ out) {
    __shared__ float flat[640], hidp[512], hid[256], hd[256], lgs[40];
    __shared__ float smx, ssum;
    __shared__ int chat;
    int t = threadIdx.x, b = blockIdx.x;
    for (int j = t; j < 640; j += 512) flat[j] = v[b * 640 + j];
    __syncthreads();
    int h = t & 255, half = t >> 8;
    {
        float a = 0.f;
        int j0 = half * 320;
        for (int j = j0; j < j0 + 320; j++) a += flat[j] * cw1[h * 640 + j];
        hidp[t] = a;
    }
    __syncthreads();
    if (t < 256) hid[t] = fmaxf(hidp[t] + hidp[t + 256] + cb1[t], 0.f);
    __syncthreads();
    if (t < 320) {
        int c = t >> 3, s = t & 7;
        float p = 0.f;
        int h0 = s * 32;
        for (int h2 = h0; h2 < h0 + 32; h2++) p += hid[h2] * cw2[c * 256 + h2];
        p += __shfl_xor(p, 1); p += __shfl_xor(p, 2); p += __shfl_xor(p, 4);
        if (s == 0) lgs[c] = p + cb2[c];
    }
    __syncthreads();
    if (t == 0) {
        float mx = lgs[0]; int am = 0;
        for (int c2 = 1; c2 < 40; c2++) if (lgs[c2] > mx) { mx = lgs[c2]; am = c2; }
        float se = 0.f;
        for (int c2 = 0; c2 < 40; c2++) se += __expf(lgs[c2] - mx);
        smx = mx; ssum = se; chat = am;
    }
    __syncthreads();
    if (t < 40) out[98304 + b * 40 + t] = __expf(lgs[t] - smx) / ssum;
    int cb = chat * 16;
    if (t < 256) {
        float ad = db1[t];
        for (int j = 0; j < 16; j++) ad += flat[cb + j] * dw1[t * 640 + cb + j];
        hd[t] = fmaxf(ad, 0.f);
    }
    __syncthreads();
    for (int o = t; o < 1536; o += 512) {
        float z = db2[o];
        for (int h2 = 0; h2 < 256; h2++) z += hd[h2] * dw2[o * 256 + h2];
        out[b * 1536 + o] = 1.f / (1.f + __expf(-z));
    }
}

extern "C" void kernel_launch(void* const* d_in, const int* in_sizes, int n_in,
                              void* d_out, int out_size, void* d_ws, size_t ws_size,
                              hipStream_t stream) {
    const float* x   = (const float*)d_in[0];
    const float* c1w = (const float*)d_in[1];
    const float* c1b = (const float*)d_in[2];
    const float* g1  = (const float*)d_in[3];
    const float* be1 = (const float*)d_in[4];
    const float* pw  = (const float*)d_in[5];
    const float* pb  = (const float*)d_in[6];
    const float* g2  = (const float*)d_in[7];
    const float* be2 = (const float*)d_in[8];
    const float* Wc  = (const float*)d_in[9];
    const float* cw1 = (const float*)d_in[10];
    const float* cb1 = (const float*)d_in[11];
    const float* cw2 = (const float*)d_in[12];
    const float* cb2 = (const float*)d_in[13];
    const float* dw1 = (const float*)d_in[14];
    const float* db1 = (const float*)d_in[15];
    const float* dw2 = (const float*)d_in[16];
    const float* db2 = (const float*)d_in[17];

    if (ws_size < WS_FLOATS_NEEDED * 4ull) return;

    float* ws  = (float*)d_ws;
    float* out = (float*)d_out;
    float* usq  = ws + O_USQ;
    float* uhat = ws + O_UHAT;
    float* hpre = ws + O_H;
    float* part = ws + O_PART;
    float* up   = ws + O_UP;
    float* sum1 = ws + O_STATS;
    float* ss1  = sum1 + 256;
    float* sum2 = ss1 + 256;
    float* ss2  = sum2 + 32;
    float* a1  = ws + O_A1;
    float* b1s = ws + O_B1S;
    float* a2  = ws + O_A2;
    float* b2s = ws + O_B2S;
    float* s0   = ws + O_S;
    float* s1   = s0 + 40960;
    float* s2   = s1 + 40960;
    float* vsum = s2 + 40960;
    float* vbuf = ws + O_V;

    hipMemsetAsync(sum1, 0, 576 * sizeof(float), stream);
    hipMemsetAsync(s0, 0, 163840 * sizeof(float), stream);

    k1_conv1<<<dim3(4, 64, 4), 256, 0, stream>>>(x, c1w, c1b, hpre);
    k2a<<<60, 256, 0, stream>>>(hpre, sum1, ss1);
    k2b<<<1, 256, 0, stream>>>(sum1, ss1, g1, be1, a1, b1s);
    k3_conv2<<<dim3(6, 64, 4), 128, 0, stream>>>(hpre, a1, b1s, pw, part);
    k4r<<<112, 256, 0, stream>>>(part, pb, up, sum2, ss2);
    k4b<<<1, 64, 0, stream>>>(sum2, ss2, g2, be2, a2, b2s);
    k5<<<10752, 256, 0, stream>>>(up, a2, b2s, usq);
    k6_uhat<<<dim3(5, 1344), 256, 0, stream>>>(usq, Wc, uhat);
    k_route<1><<<dim3(42, 64), 256, 0, stream>>>(uhat, nullptr, s0);
    k8<<<160, 256, 0, stream>>>(s0, vbuf, vsum, 1);
    k_route<0><<<dim3(42, 64), 256, 0, stream>>>(uhat, vsum, s1);
    k8<<<160, 256, 0, stream>>>(s1, vbuf, vsum, 1);
    k_route<0><<<dim3(42, 64), 256, 0, stream>>>(uhat, vsum, s2);
    k8<<<160, 256, 0, stream>>>(s2, vbuf, vsum, 0);
    k10_head<<<64, 512, 0, stream>>>(vbuf, cw1, cb1, cw2, cb2, dw1, db1, dw2, db2, out);
}

// Round 6
// 570.109 us; speedup vs baseline: 1.1618x; 1.1618x over previous
//
#include <hip/hip_runtime.h>
#include <math.h>

// ---------------- problem constants ----------------
#define BB_ 64
#define P_  24
#define C_  40
#define WIN_ 64
#define L1_ 60
#define L2_ 56
#define R_  1344

// ---------------- ws layout (float offsets) ----------------
#define O_USQ   0ull
#define O_UHAT  2752512ull
#define O_H     2752512ull          // alias (dead before k6 writes uhat)
#define O_PART  3735552ull          // 4 * 2752512 floats of conv2 K-split partials
#define O_UP    14745600ull
#define O_STATS 57802752ull
#define O_A1    57803328ull
#define O_B1S   57803584ull
#define O_A2    57803840ull
#define O_B2S   57803872ull
#define O_S     57803904ull         // s0,s1,s2,vsum each 40960
#define O_V     57967744ull
#define WS_FLOATS_NEEDED 58008704ull

__device__ __forceinline__ float dot4f(float4 a, float4 b) {
    return a.x*b.x + a.y*b.y + a.z*b.z + a.w*b.w;
}

// ============ K1: conv1 (24->256, k=5) + bias, h layout (b, l, o) ============
__global__ void k1_conv1(const float* __restrict__ x, const float* __restrict__ w1,
                         const float* __restrict__ c1b, float* __restrict__ h) {
    __shared__ float xs[24 * 20];
    __shared__ float wl[64 * 121];
    int t = threadIdx.x;
    int lq = blockIdx.x, b = blockIdx.y, ocg = blockIdx.z;
    for (int idx = t; idx < 456; idx += 256) {
        int p = idx / 19, tau = idx - p * 19;
        xs[p * 20 + tau] = x[b * 1536 + (lq * 15 + tau) * 24 + p];
    }
    for (int idx = t; idx < 7680; idx += 256) {
        int o_ = idx / 120, cix = idx - o_ * 120;
        wl[o_ * 121 + cix] = w1[(ocg * 64 + o_) * 120 + cix];
    }
    __syncthreads();
    int g = t >> 6;
    int ol = t & 63;
    int LV = (g < 3) ? 4 : 3;
    int o = ocg * 64 + ol;
    float acc[4] = {0.f, 0.f, 0.f, 0.f};
    for (int p = 0; p < 24; p++) {
        float4 xa = *(const float4*)&xs[p * 20 + g * 4];
        float4 xb = *(const float4*)&xs[p * 20 + g * 4 + 4];
        float xr[8] = {xa.x, xa.y, xa.z, xa.w, xb.x, xb.y, xb.z, xb.w};
        #pragma unroll
        for (int k = 0; k < 5; k++) {
            float w = wl[ol * 121 + p * 5 + k];
            #pragma unroll
            for (int li = 0; li < 4; li++) acc[li] += xr[li + k] * w;
        }
    }
    for (int li = 0; li < LV; li++) {
        int l = lq * 15 + g * 4 + li;
        h[(size_t)(b * 60 + l) * 256 + o] = acc[li] + c1b[o];
    }
}

// ============ K2a: BN1 stats ============
__global__ void k2a(const float* __restrict__ h, float* __restrict__ sum1, float* __restrict__ ss1) {
    int t = threadIdx.x;
    float s = 0.f, q = 0.f;
    for (int i = 0; i < 64; i++) {
        float v = h[(size_t)(blockIdx.x * 64 + i) * 256 + t];
        s += v; q += v * v;
    }
    atomicAdd(&sum1[t], s);
    atomicAdd(&ss1[t], q);
}

__global__ void k2b(const float* __restrict__ sum1, const float* __restrict__ ss1,
                    const float* __restrict__ g, const float* __restrict__ be,
                    float* __restrict__ a1, float* __restrict__ b1s) {
    int o = threadIdx.x;
    float m = sum1[o] * (1.f / 3840.f);
    float v = ss1[o] * (1.f / 3840.f) - m * m;
    float a = g[o] / sqrtf(v + 1e-5f);
    a1[o] = a;
    b1s[o] = be[o] - m * a;
}

// ============ K3: primary conv (256->768, k=5), K-split x4, 2 batches/block ============
// grid (6 o2tile, 32 bpair, 4 ks), block 128. Thread tile: 2b x 8l x 8o2.
// LDS: hs 2x980 + wl 80x132 = 50 KB -> 3 blocks/CU; 8 barriers/block, 10240 FMA/thread/chunk.
__global__ __launch_bounds__(128) void k3_conv2(
        const float* __restrict__ h, const float* __restrict__ a1, const float* __restrict__ b1s,
        const float* __restrict__ w2, float* __restrict__ part) {
    __shared__ float hs[1960];       // 2 b x (16 ic x 60 l) + pad, stride 980 per b
    __shared__ float wl[10560];      // (16 ic * 5 k) rows x 128 o2, stride 132
    int t = threadIdx.x;
    int tile = blockIdx.x, bp = blockIdx.y, ks = blockIdx.z;
    int b0 = bp * 2;
    int lane = t & 63, wv_ = t >> 6;
    int og = lane >> 3, lg = lane & 7;
    int o2b = tile * 128 + wv_ * 64 + og * 8;
    float acc[2][8][8];
    #pragma unroll
    for (int bb = 0; bb < 2; bb++)
        #pragma unroll
        for (int i = 0; i < 8; i++)
            #pragma unroll
            for (int j = 0; j < 8; j++) acc[bb][i][j] = 0.f;

    int oc0 = ks * 64;
    for (int oc = oc0; oc < oc0 + 64; oc += 16) {
        __syncthreads();
        // stage h for both batches: 2 x 960 floats, BN1+ReLU applied
        #pragma unroll
        for (int bb = 0; bb < 2; bb++) {
            for (int idx = t; idx < 960; idx += 128) {
                int o_ = idx & 15, l = idx >> 4;
                float v = h[(size_t)((b0 + bb) * 60 + l) * 256 + oc + o_];
                hs[bb * 980 + o_ * 60 + l] = fmaxf(a1[oc + o_] * v + b1s[oc + o_], 0.f);
            }
        }
        // stage w2: thread t owns o2-column t; float4 global loads, conflict-free scalar writes
        {
            const float* wrow = &w2[(size_t)(tile * 128 + t) * 1280 + oc * 5];
            #pragma unroll
            for (int outer = 0; outer < 20; outer++) {
                float4 v = *(const float4*)&wrow[outer * 4];
                wl[(outer * 4 + 0) * 132 + t] = v.x;
                wl[(outer * 4 + 1) * 132 + t] = v.y;
                wl[(outer * 4 + 2) * 132 + t] = v.z;
                wl[(outer * 4 + 3) * 132 + t] = v.w;
            }
        }
        __syncthreads();
        for (int o_ = 0; o_ < 16; o_++) {
            float hw[2][12];
            #pragma unroll
            for (int bb = 0; bb < 2; bb++) {
                const float4* h4 = (const float4*)&hs[bb * 980 + o_ * 60];
                float4 ha = h4[lg * 2], hb = h4[lg * 2 + 1], hc = h4[lg * 2 + 2];
                hw[bb][0] = ha.x; hw[bb][1] = ha.y; hw[bb][2] = ha.z; hw[bb][3] = ha.w;
                hw[bb][4] = hb.x; hw[bb][5] = hb.y; hw[bb][6] = hb.z; hw[bb][7] = hb.w;
                hw[bb][8] = hc.x; hw[bb][9] = hc.y; hw[bb][10] = hc.z; hw[bb][11] = hc.w;
            }
            #pragma unroll
            for (int k = 0; k < 5; k++) {
                const float4* w4 = (const float4*)&wl[(o_ * 5 + k) * 132];
                float4 wa = w4[wv_ * 16 + og * 2];
                float4 wb = w4[wv_ * 16 + og * 2 + 1];
                float wr[8] = {wa.x, wa.y, wa.z, wa.w, wb.x, wb.y, wb.z, wb.w};
                #pragma unroll
                for (int bb = 0; bb < 2; bb++)
                    #pragma unroll
                    for (int li = 0; li < 8; li++)
                        #pragma unroll
                        for (int oi = 0; oi < 8; oi++)
                            acc[bb][li][oi] += hw[bb][li + k] * wr[oi];
            }
        }
    }
    if (lg < 7) {
        float* dst = part + (size_t)ks * 2752512;
        #pragma unroll
        for (int bb = 0; bb < 2; bb++) {
            #pragma unroll
            for (int li = 0; li < 8; li++) {
                int l = lg * 8 + li;
                size_t base = (size_t)(b0 + bb) * 43008 + (size_t)l * 768 + o2b;
                float4 v0 = {acc[bb][li][0], acc[bb][li][1], acc[bb][li][2], acc[bb][li][3]};
                float4 v1 = {acc[bb][li][4], acc[bb][li][5], acc[bb][li][6], acc[bb][li][7]};
                *(float4*)&dst[base] = v0;
                *(float4*)&dst[base + 4] = v1;
            }
        }
    }
}

// ============ K4r: reduce K-split partials + bias -> up, and BN2 stats ============
__global__ void k4r(const float* __restrict__ part, const float* __restrict__ pb,
                    float* __restrict__ up, float* __restrict__ sum2, float* __restrict__ ss2) {
    __shared__ float rs[256], rq[256];
    int t = threadIdx.x;
    float s = 0.f, q = 0.f;
    for (int i = 0; i < 32; i++) {
        size_t row = (size_t)(blockIdx.x * 32 + i) * 768;
        for (int c0 = 0; c0 < 768; c0 += 256) {
            int idx = c0 + t;
            float v = part[row + idx] + part[2752512ull + row + idx]
                    + part[2ull * 2752512ull + row + idx] + part[3ull * 2752512ull + row + idx]
                    + pb[idx];
            up[row + idx] = v;
            s += v; q += v * v;
        }
    }
    rs[t] = s; rq[t] = q;
    __syncthreads();
    if (t < 32) {
        float S = 0.f, Q = 0.f;
        for (int g2 = 0; g2 < 8; g2++) { S += rs[t + 32 * g2]; Q += rq[t + 32 * g2]; }
        atomicAdd(&sum2[t], S);
        atomicAdd(&ss2[t], Q);
    }
}

__global__ void k4b(const float* __restrict__ sum2, const float* __restrict__ ss2,
                    const float* __restrict__ g, const float* __restrict__ be,
                    float* __restrict__ a2, float* __restrict__ b2s) {
    int j = threadIdx.x;
    if (j >= 32) return;
    float m = sum2[j] * (1.f / 86016.f);
    float v = ss2[j] * (1.f / 86016.f) - m * m;
    float a = g[j] / sqrtf(v + 1e-5f);
    a2[j] = a;
    b2s[j] = be[j] - m * a;
}

// ============ K5: BN2 apply + squash over 32 -> usq (b, r, i) ============
__global__ void k5(const float* __restrict__ up, const float* __restrict__ a2,
                   const float* __restrict__ b2s, float* __restrict__ usq) {
    int t = threadIdx.x;
    int row = blockIdx.x * 8 + (t >> 5);
    int j = t & 31;
    int b = row / 1344, r = row - b * 1344;
    int p = r / 56, l = r - p * 56;
    float v = up[(size_t)b * 43008 + (size_t)l * 768 + p * 32 + j];
    float xv = a2[j] * v + b2s[j];
    float sq = xv * xv;
    #pragma unroll
    for (int m = 16; m >= 1; m >>= 1) sq += __shfl_xor(sq, m, 32);
    float scale = (sq / (1.f + sq)) / (sqrtf(sq) + 1e-8f);
    usq[(size_t)row * 32 + j] = xv * scale;
}

// ============ K6: batched GEMM per r: uhat[b, cd] = U[b,i] . W[cd,i] ============
__global__ __launch_bounds__(256) void k6_uhat(const float* __restrict__ usq,
                                               const float* __restrict__ W,
                                               float* __restrict__ uh) {
    __shared__ float us[64 * 36];
    __shared__ float wl[128 * 36];
    int t = threadIdx.x;
    int cdt = blockIdx.x, r = blockIdx.y;

    #pragma unroll
    for (int q = 0; q < 2; q++) {
        int idx4 = q * 256 + t;
        int b = idx4 >> 3, i4 = idx4 & 7;
        float4 v = *(const float4*)&usq[(size_t)(b * 1344 + r) * 32 + i4 * 4];
        *(float4*)&us[b * 36 + i4 * 4] = v;
    }
    #pragma unroll
    for (int q = 0; q < 4; q++) {
        int idx4 = q * 256 + t;
        int c_l = idx4 >> 7;
        int rest4 = idx4 & 127;
        float4 v = *(const float4*)&W[(size_t)(cdt * 8 + c_l) * 688128ull +
                                      (size_t)r * 512 + rest4 * 4];
        int cd_l = c_l * 16 + (rest4 >> 3);
        int i4 = rest4 & 7;
        *(float4*)&wl[cd_l * 36 + i4 * 4] = v;
    }
    __syncthreads();

    int tb = t & 7, tcd = t >> 3;
    float acc[8][4];
    #pragma unroll
    for (int i = 0; i < 8; i++)
        #pragma unroll
        for (int j = 0; j < 4; j++) acc[i][j] = 0.f;

    #pragma unroll
    for (int k4 = 0; k4 < 8; k4++) {
        float4 wv[4], ub[8];
        #pragma unroll
        for (int j = 0; j < 4; j++)
            wv[j] = *(const float4*)&wl[(tcd * 4 + j) * 36 + k4 * 4];
        #pragma unroll
        for (int bj = 0; bj < 8; bj++)
            ub[bj] = *(const float4*)&us[(bj * 8 + tb) * 36 + k4 * 4];
        #pragma unroll
        for (int bj = 0; bj < 8; bj++)
            #pragma unroll
            for (int j = 0; j < 4; j++)
                acc[bj][j] += dot4f(ub[bj], wv[j]);
    }

    #pragma unroll
    for (int bj = 0; bj < 8; bj++) {
        int b = bj * 8 + tb;
        float4 o = {acc[bj][0], acc[bj][1], acc[bj][2], acc[bj][3]};
        *(float4*)&uh[(size_t)(b * 1344 + r) * 640 + cdt * 128 + tcd * 4] = o;
    }
}

// ============ K_route: 8 r per wave, grid (42, 64) ============
template<int UNIFORM>
__global__ void k_route(const float* __restrict__ uh, const float* __restrict__ vsum,
                        float* __restrict__ sout) {
    __shared__ float sl[2560];
    int t = threadIdx.x, wid = t >> 6, lane = t & 63;
    int b = blockIdx.y, rt = blockIdx.x;
    bool act = lane < 40;
    int c = act ? lane : 0;
    float4 vs0 = {0,0,0,0}, vs1 = vs0, vs2 = vs0, vs3 = vs0;
    if (UNIFORM == 0 && act) {
        const float4* vp = (const float4*)&vsum[b * 640 + c * 16];
        vs0 = vp[0]; vs1 = vp[1]; vs2 = vp[2]; vs3 = vp[3];
    }
    float4 ac0 = {0,0,0,0}, ac1 = ac0, ac2 = ac0, ac3 = ac0;
    for (int i = 0; i < 8; i++) {
        int r = rt * 32 + wid * 8 + i;
        const float4* u4 = (const float4*)&uh[((size_t)(b * 1344 + r) * 40 + c) * 16];
        float4 a0 = {0,0,0,0}, a1 = a0, a2 = a0, a3 = a0;
        if (act) { a0 = u4[0]; a1 = u4[1]; a2 = u4[2]; a3 = u4[3]; }
        float w;
        if (UNIFORM) {
            w = 0.025f;
        } else {
            float dt = act ? (dot4f(a0, vs0) + dot4f(a1, vs1) + dot4f(a2, vs2) + dot4f(a3, vs3))
                           : -1e30f;
            float mx = dt;
            #pragma unroll
            for (int m2 = 32; m2 >= 1; m2 >>= 1) mx = fmaxf(mx, __shfl_xor(mx, m2));
            float e = act ? __expf(dt - mx) : 0.f;
            float se = e;
            #pragma unroll
            for (int m2 = 32; m2 >= 1; m2 >>= 1) se += __shfl_xor(se, m2);
            w = e / se;
        }
        ac0.x += w * a0.x; ac0.y += w * a0.y; ac0.z += w * a0.z; ac0.w += w * a0.w;
        ac1.x += w * a1.x; ac1.y += w * a1.y; ac1.z += w * a1.z; ac1.w += w * a1.w;
        ac2.x += w * a2.x; ac2.y += w * a2.y; ac2.z += w * a2.z; ac2.w += w * a2.w;
        ac3.x += w * a3.x; ac3.y += w * a3.y; ac3.z += w * a3.z; ac3.w += w * a3.w;
    }
    if (act) {
        float4* sp = (float4*)&sl[wid * 640 + c * 16];
        sp[0] = ac0; sp[1] = ac1; sp[2] = ac2; sp[3] = ac3;
    }
    __syncthreads();
    for (int jj = t; jj < 640; jj += 256)
        atomicAdd(&sout[b * 640 + jj], sl[jj] + sl[640 + jj] + sl[1280 + jj] + sl[1920 + jj]);
}

// ============ K8: squash s -> v ============
__global__ void k8(const float* __restrict__ sin, float* __restrict__ vout,
                   float* __restrict__ vsum, int addsum) {
    int t = threadIdx.x;
    int row = blockIdx.x * 16 + (t >> 4);
    int d = t & 15;
    float v = sin[row * 16 + d];
    float sq = v * v;
    #pragma unroll
    for (int m = 8; m >= 1; m >>= 1) sq += __shfl_xor(sq, m, 16);
    float scale = (sq / (1.f + sq)) / (sqrtf(sq) + 1e-8f);
    float o = v * scale;
    vout[row * 16 + d] = o;
    if (addsum) vsum[row * 16 + d] += o;
}

// ============ K10: head (512 thr) ============
__global__ void k10_head(const float* __restrict__ v,
                         const float* __restrict__ cw1, const float* __restrict__ cb1,
                         const float* __restrict__ cw2, const float* __restrict__ cb2,
                         const float* __restrict__ dw1, const float* __restrict__ db1,
                         const float* __restrict__ dw2, const float* __restrict__ db2,
                         float* __restrict__ out) {
    __shared__ float flat[640], hidp[512], hid[256], hd[256], lgs[40];
    __shared__ float smx, ssum;
    __shared__ int chat;
    int t = threadIdx.x, b = blockIdx.x;
    for (int j = t; j < 640; j += 512) flat[j] = v[b * 640 + j];
    __syncthreads();
    int h = t & 255, half = t >> 8;
    {
        float a = 0.f;
        int j0 = half * 320;
        for (int j = j0; j < j0 + 320; j++) a += flat[j] * cw1[h * 640 + j];
        hidp[t] = a;
    }
    __syncthreads();
    if (t < 256) hid[t] = fmaxf(hidp[t] + hidp[t + 256] + cb1[t], 0.f);
    __syncthreads();
    if (t < 320) {
        int c = t >> 3, s = t & 7;
        float p = 0.f;
        int h0 = s * 32;
        for (int h2 = h0; h2 < h0 + 32; h2++) p += hid[h2] * cw2[c * 256 + h2];
        p += __shfl_xor(p, 1); p += __shfl_xor(p, 2); p += __shfl_xor(p, 4);
        if (s == 0) lgs[c] = p + cb2[c];
    }
    __syncthreads();
    if (t == 0) {
        float mx = lgs[0]; int am = 0;
        for (int c2 = 1; c2 < 40; c2++) if (lgs[c2] > mx) { mx = lgs[c2]; am = c2; }
        float se = 0.f;
        for (int c2 = 0; c2 < 40; c2++) se += __expf(lgs[c2] - mx);
        smx = mx; ssum = se; chat = am;
    }
    __syncthreads();
    if (t < 40) out[98304 + b * 40 + t] = __expf(lgs[t] - smx) / ssum;
    int cb = chat * 16;
    if (t < 256) {
        float ad = db1[t];
        for (int j = 0; j < 16; j++) ad += flat[cb + j] * dw1[t * 640 + cb + j];
        hd[t] = fmaxf(ad, 0.f);
    }
    __syncthreads();
    for (int o = t; o < 1536; o += 512) {
        float z = db2[o];
        for (int h2 = 0; h2 < 256; h2++) z += hd[h2] * dw2[o * 256 + h2];
        out[b * 1536 + o] = 1.f / (1.f + __expf(-z));
    }
}

extern "C" void kernel_launch(void* const* d_in, const int* in_sizes, int n_in,
                              void* d_out, int out_size, void* d_ws, size_t ws_size,
                              hipStream_t stream) {
    const float* x   = (const float*)d_in[0];
    const float* c1w = (const float*)d_in[1];
    const float* c1b = (const float*)d_in[2];
    const float* g1  = (const float*)d_in[3];
    const float* be1 = (const float*)d_in[4];
    const float* pw  = (const float*)d_in[5];
    const float* pb  = (const float*)d_in[6];
    const float* g2  = (const float*)d_in[7];
    const float* be2 = (const float*)d_in[8];
    const float* Wc  = (const float*)d_in[9];
    const float* cw1 = (const float*)d_in[10];
    const float* cb1 = (const float*)d_in[11];
    const float* cw2 = (const float*)d_in[12];
    const float* cb2 = (const float*)d_in[13];
    const float* dw1 = (const float*)d_in[14];
    const float* db1 = (const float*)d_in[15];
    const float* dw2 = (const float*)d_in[16];
    const float* db2 = (const float*)d_in[17];

    if (ws_size < WS_FLOATS_NEEDED * 4ull) return;

    float* ws  = (float*)d_ws;
    float* out = (float*)d_out;
    float* usq  = ws + O_USQ;
    float* uhat = ws + O_UHAT;
    float* hpre = ws + O_H;
    float* part = ws + O_PART;
    float* up   = ws + O_UP;
    float* sum1 = ws + O_STATS;
    float* ss1  = sum1 + 256;
    float* sum2 = ss1 + 256;
    float* ss2  = sum2 + 32;
    float* a1  = ws + O_A1;
    float* b1s = ws + O_B1S;
    float* a2  = ws + O_A2;
    float* b2s = ws + O_B2S;
    float* s0   = ws + O_S;
    float* s1   = s0 + 40960;
    float* s2   = s1 + 40960;
    float* vsum = s2 + 40960;
    float* vbuf = ws + O_V;

    hipMemsetAsync(sum1, 0, 576 * sizeof(float), stream);
    hipMemsetAsync(s0, 0, 163840 * sizeof(float), stream);

    k1_conv1<<<dim3(4, 64, 4), 256, 0, stream>>>(x, c1w, c1b, hpre);
    k2a<<<60, 256, 0, stream>>>(hpre, sum1, ss1);
    k2b<<<1, 256, 0, stream>>>(sum1, ss1, g1, be1, a1, b1s);
    k3_conv2<<<dim3(6, 32, 4), 128, 0, stream>>>(hpre, a1, b1s, pw, part);
    k4r<<<112, 256, 0, stream>>>(part, pb, up, sum2, ss2);
    k4b<<<1, 64, 0, stream>>>(sum2, ss2, g2, be2, a2, b2s);
    k5<<<10752, 256, 0, stream>>>(up, a2, b2s, usq);
    k6_uhat<<<dim3(5, 1344), 256, 0, stream>>>(usq, Wc, uhat);
    k_route<1><<<dim3(42, 64), 256, 0, stream>>>(uhat, nullptr, s0);
    k8<<<160, 256, 0, stream>>>(s0, vbuf, vsum, 1);
    k_route<0><<<dim3(42, 64), 256, 0, stream>>>(uhat, vsum, s1);
    k8<<<160, 256, 0, stream>>>(s1, vbuf, vsum, 1);
    k_route<0><<<dim3(42, 64), 256, 0, stream>>>(uhat, vsum, s2);
    k8<<<160, 256, 0, stream>>>(s2, vbuf, vsum, 0);
    k10_head<<<64, 512, 0, stream>>>(vbuf, cw1, cb1, cw2, cb2, dw1, db1, dw2, db2, out);
}

// Round 7
// 515.144 us; speedup vs baseline: 1.2858x; 1.1067x over previous
//
#include <hip/hip_runtime.h>
#include <math.h>

// ---------------- problem constants ----------------
#define BB_ 64
#define P_  24
#define C_  40
#define WIN_ 64
#define L1_ 60
#define L2_ 56
#define R_  1344

// ---------------- ws layout (float offsets) ----------------
// usq [0, 2752512)
// uhat (bf16, 55050240 ushorts = 27525120 floats) at [2752512, 30277632)
// part/up overlay inside uhat region (dead before k6 writes uhat)
#define O_USQ   0ull
#define O_UHAT  2752512ull
#define O_H     30277632ull         // hpre: 64*60*256 = 983040 floats (outside uhat region)
#define O_PART  3735552ull          // 8 * 2752512 floats, alias in uhat region
#define O_UP    25755648ull         // 2752512 floats, alias in uhat region
#define O_STATS 57802752ull
#define O_A1    57803328ull
#define O_B1S   57803584ull
#define O_A2    57803840ull
#define O_B2S   57803872ull
#define O_S     57803904ull         // s0,s1,s2,vsum each 40960
#define O_V     57967744ull
#define WS_FLOATS_NEEDED 58008704ull

#define PART_STRIDE 2752512ull

__device__ __forceinline__ float dot4f(float4 a, float4 b) {
    return a.x*b.x + a.y*b.y + a.z*b.z + a.w*b.w;
}

__device__ __forceinline__ unsigned short f2bf(float x) {
    unsigned int u = __float_as_uint(x);
    u += 0x7fffu + ((u >> 16) & 1u);       // RTNE
    return (unsigned short)(u >> 16);
}
__device__ __forceinline__ float bfl(unsigned int u) {   // low ushort -> float
    return __uint_as_float(u << 16);
}
__device__ __forceinline__ float bfh(unsigned int u) {   // high ushort -> float
    return __uint_as_float(u & 0xffff0000u);
}

// ============ K1: conv1 (24->256, k=5) + bias, h layout (b, l, o) ============
__global__ void k1_conv1(const float* __restrict__ x, const float* __restrict__ w1,
                         const float* __restrict__ c1b, float* __restrict__ h) {
    __shared__ float xs[24 * 20];
    __shared__ float wl[64 * 121];
    int t = threadIdx.x;
    int lq = blockIdx.x, b = blockIdx.y, ocg = blockIdx.z;
    for (int idx = t; idx < 456; idx += 256) {
        int p = idx / 19, tau = idx - p * 19;
        xs[p * 20 + tau] = x[b * 1536 + (lq * 15 + tau) * 24 + p];
    }
    for (int idx = t; idx < 7680; idx += 256) {
        int o_ = idx / 120, cix = idx - o_ * 120;
        wl[o_ * 121 + cix] = w1[(ocg * 64 + o_) * 120 + cix];
    }
    __syncthreads();
    int g = t >> 6;
    int ol = t & 63;
    int LV = (g < 3) ? 4 : 3;
    int o = ocg * 64 + ol;
    float acc[4] = {0.f, 0.f, 0.f, 0.f};
    for (int p = 0; p < 24; p++) {
        float4 xa = *(const float4*)&xs[p * 20 + g * 4];
        float4 xb = *(const float4*)&xs[p * 20 + g * 4 + 4];
        float xr[8] = {xa.x, xa.y, xa.z, xa.w, xb.x, xb.y, xb.z, xb.w};
        #pragma unroll
        for (int k = 0; k < 5; k++) {
            float w = wl[ol * 121 + p * 5 + k];
            #pragma unroll
            for (int li = 0; li < 4; li++) acc[li] += xr[li + k] * w;
        }
    }
    for (int li = 0; li < LV; li++) {
        int l = lq * 15 + g * 4 + li;
        h[(size_t)(b * 60 + l) * 256 + o] = acc[li] + c1b[o];
    }
}

// ============ K2a: BN1 stats ============
__global__ void k2a(const float* __restrict__ h, float* __restrict__ sum1, float* __restrict__ ss1) {
    int t = threadIdx.x;
    float s = 0.f, q = 0.f;
    for (int i = 0; i < 64; i++) {
        float v = h[(size_t)(blockIdx.x * 64 + i) * 256 + t];
        s += v; q += v * v;
    }
    atomicAdd(&sum1[t], s);
    atomicAdd(&ss1[t], q);
}

__global__ void k2b(const float* __restrict__ sum1, const float* __restrict__ ss1,
                    const float* __restrict__ g, const float* __restrict__ be,
                    float* __restrict__ a1, float* __restrict__ b1s) {
    int o = threadIdx.x;
    float m = sum1[o] * (1.f / 3840.f);
    float v = ss1[o] * (1.f / 3840.f) - m * m;
    float a = g[o] / sqrtf(v + 1e-5f);
    a1[o] = a;
    b1s[o] = be[o] - m * a;
}

// ============ K3: primary conv (256->768, k=5), K-split x8, 4 batches/block ============
// grid (6 o2tile, 16 bquad, 8 ks), block 256 (4 waves).
// wave w: batch pair (w>>1), o2 half (w&1). Thread tile: 2b x 8l x 8o2.
// LDS: hs 4x980 + wl 80x132 = 56.6 KB -> 2 blocks/CU = 8 waves/CU.
__global__ __launch_bounds__(256) void k3_conv2(
        const float* __restrict__ h, const float* __restrict__ a1, const float* __restrict__ b1s,
        const float* __restrict__ w2, float* __restrict__ part) {
    __shared__ float hs[3920];       // 4 b x (16 ic x 60 l) + pad, stride 980 per b
    __shared__ float wl[10560];      // (16 ic * 5 k) rows x 128 o2, stride 132
    int t = threadIdx.x;
    int tile = blockIdx.x, bq = blockIdx.y, ks = blockIdx.z;
    int b0 = bq * 4;
    int wv = t >> 6;
    int bp2 = wv >> 1;               // which batch pair of the quad
    int o2h = wv & 1;                // which o2 half
    int lane = t & 63;
    int og = lane >> 3, lg = lane & 7;
    int o2b = tile * 128 + o2h * 64 + og * 8;
    float acc[2][8][8];
    #pragma unroll
    for (int bb = 0; bb < 2; bb++)
        #pragma unroll
        for (int i = 0; i < 8; i++)
            #pragma unroll
            for (int j = 0; j < 8; j++) acc[bb][i][j] = 0.f;

    int oc0 = ks * 32;
    for (int oc = oc0; oc < oc0 + 32; oc += 16) {
        __syncthreads();
        // stage h for 4 batches (BN1+ReLU applied)
        #pragma unroll
        for (int bb4 = 0; bb4 < 4; bb4++) {
            for (int idx = t; idx < 960; idx += 256) {
                int o_ = idx & 15, l = idx >> 4;
                float v = h[(size_t)((b0 + bb4) * 60 + l) * 256 + oc + o_];
                hs[bb4 * 980 + o_ * 60 + l] = fmaxf(a1[oc + o_] * v + b1s[oc + o_], 0.f);
            }
        }
        // stage w2: col = t&127, row-group = t>>7 (40 rows each); conflict-free writes
        {
            int col = t & 127, rg = t >> 7;
            const float* wrow = &w2[(size_t)(tile * 128 + col) * 1280 + oc * 5 + rg * 40];
            #pragma unroll
            for (int outer = 0; outer < 10; outer++) {
                float4 v = *(const float4*)&wrow[outer * 4];
                int rbase = rg * 40 + outer * 4;
                wl[(rbase + 0) * 132 + col] = v.x;
                wl[(rbase + 1) * 132 + col] = v.y;
                wl[(rbase + 2) * 132 + col] = v.z;
                wl[(rbase + 3) * 132 + col] = v.w;
            }
        }
        __syncthreads();
        for (int o_ = 0; o_ < 16; o_++) {
            float hw[2][12];
            #pragma unroll
            for (int bb = 0; bb < 2; bb++) {
                const float4* h4 = (const float4*)&hs[(bp2 * 2 + bb) * 980 + o_ * 60];
                float4 ha = h4[lg * 2], hb = h4[lg * 2 + 1], hc = h4[lg * 2 + 2];
                hw[bb][0] = ha.x; hw[bb][1] = ha.y; hw[bb][2] = ha.z; hw[bb][3] = ha.w;
                hw[bb][4] = hb.x; hw[bb][5] = hb.y; hw[bb][6] = hb.z; hw[bb][7] = hb.w;
                hw[bb][8] = hc.x; hw[bb][9] = hc.y; hw[bb][10] = hc.z; hw[bb][11] = hc.w;
            }
            #pragma unroll
            for (int k = 0; k < 5; k++) {
                const float4* w4 = (const float4*)&wl[(o_ * 5 + k) * 132];
                float4 wa = w4[o2h * 16 + og * 2];
                float4 wb = w4[o2h * 16 + og * 2 + 1];
                float wr[8] = {wa.x, wa.y, wa.z, wa.w, wb.x, wb.y, wb.z, wb.w};
                #pragma unroll
                for (int bb = 0; bb < 2; bb++)
                    #pragma unroll
                    for (int li = 0; li < 8; li++)
                        #pragma unroll
                        for (int oi = 0; oi < 8; oi++)
                            acc[bb][li][oi] += hw[bb][li + k] * wr[oi];
            }
        }
    }
    if (lg < 7) {
        float* dst = part + (size_t)ks * PART_STRIDE;
        #pragma unroll
        for (int bb = 0; bb < 2; bb++) {
            int b = b0 + bp2 * 2 + bb;
            #pragma unroll
            for (int li = 0; li < 8; li++) {
                int l = lg * 8 + li;
                size_t base = (size_t)b * 43008 + (size_t)l * 768 + o2b;
                float4 v0 = {acc[bb][li][0], acc[bb][li][1], acc[bb][li][2], acc[bb][li][3]};
                float4 v1 = {acc[bb][li][4], acc[bb][li][5], acc[bb][li][6], acc[bb][li][7]};
                *(float4*)&dst[base] = v0;
                *(float4*)&dst[base + 4] = v1;
            }
        }
    }
}

// ============ K4r: reduce 8 K-split partials + bias -> up, and BN2 stats ============
__global__ void k4r(const float* __restrict__ part, const float* __restrict__ pb,
                    float* __restrict__ up, float* __restrict__ sum2, float* __restrict__ ss2) {
    __shared__ float rs[256], rq[256];
    int t = threadIdx.x;
    float s = 0.f, q = 0.f;
    for (int i = 0; i < 32; i++) {
        size_t row = (size_t)(blockIdx.x * 32 + i) * 768;
        for (int c0 = 0; c0 < 768; c0 += 256) {
            int idx = c0 + t;
            float v = pb[idx];
            #pragma unroll
            for (int kk = 0; kk < 8; kk++)
                v += part[(size_t)kk * PART_STRIDE + row + idx];
            up[row + idx] = v;
            s += v; q += v * v;
        }
    }
    rs[t] = s; rq[t] = q;
    __syncthreads();
    if (t < 32) {
        float S = 0.f, Q = 0.f;
        for (int g2 = 0; g2 < 8; g2++) { S += rs[t + 32 * g2]; Q += rq[t + 32 * g2]; }
        atomicAdd(&sum2[t], S);
        atomicAdd(&ss2[t], Q);
    }
}

__global__ void k4b(const float* __restrict__ sum2, const float* __restrict__ ss2,
                    const float* __restrict__ g, const float* __restrict__ be,
                    float* __restrict__ a2, float* __restrict__ b2s) {
    int j = threadIdx.x;
    if (j >= 32) return;
    float m = sum2[j] * (1.f / 86016.f);
    float v = ss2[j] * (1.f / 86016.f) - m * m;
    float a = g[j] / sqrtf(v + 1e-5f);
    a2[j] = a;
    b2s[j] = be[j] - m * a;
}

// ============ K5: BN2 apply + squash over 32 -> usq (b, r, i) ============
__global__ void k5(const float* __restrict__ up, const float* __restrict__ a2,
                   const float* __restrict__ b2s, float* __restrict__ usq) {
    int t = threadIdx.x;
    int row = blockIdx.x * 8 + (t >> 5);
    int j = t & 31;
    int b = row / 1344, r = row - b * 1344;
    int p = r / 56, l = r - p * 56;
    float v = up[(size_t)b * 43008 + (size_t)l * 768 + p * 32 + j];
    float xv = a2[j] * v + b2s[j];
    float sq = xv * xv;
    #pragma unroll
    for (int m = 16; m >= 1; m >>= 1) sq += __shfl_xor(sq, m, 32);
    float scale = (sq / (1.f + sq)) / (sqrtf(sq) + 1e-8f);
    usq[(size_t)row * 32 + j] = xv * scale;
}

// ============ K6: batched GEMM per r, bf16 output ============
__global__ __launch_bounds__(256) void k6_uhat(const float* __restrict__ usq,
                                               const float* __restrict__ W,
                                               unsigned short* __restrict__ uhb) {
    __shared__ float us[64 * 36];
    __shared__ float wl[128 * 36];
    int t = threadIdx.x;
    int cdt = blockIdx.x, r = blockIdx.y;

    #pragma unroll
    for (int q = 0; q < 2; q++) {
        int idx4 = q * 256 + t;
        int b = idx4 >> 3, i4 = idx4 & 7;
        float4 v = *(const float4*)&usq[(size_t)(b * 1344 + r) * 32 + i4 * 4];
        *(float4*)&us[b * 36 + i4 * 4] = v;
    }
    #pragma unroll
    for (int q = 0; q < 4; q++) {
        int idx4 = q * 256 + t;
        int c_l = idx4 >> 7;
        int rest4 = idx4 & 127;
        float4 v = *(const float4*)&W[(size_t)(cdt * 8 + c_l) * 688128ull +
                                      (size_t)r * 512 + rest4 * 4];
        int cd_l = c_l * 16 + (rest4 >> 3);
        int i4 = rest4 & 7;
        *(float4*)&wl[cd_l * 36 + i4 * 4] = v;
    }
    __syncthreads();

    int tb = t & 7, tcd = t >> 3;
    float acc[8][4];
    #pragma unroll
    for (int i = 0; i < 8; i++)
        #pragma unroll
        for (int j = 0; j < 4; j++) acc[i][j] = 0.f;

    #pragma unroll
    for (int k4 = 0; k4 < 8; k4++) {
        float4 wv[4], ub[8];
        #pragma unroll
        for (int j = 0; j < 4; j++)
            wv[j] = *(const float4*)&wl[(tcd * 4 + j) * 36 + k4 * 4];
        #pragma unroll
        for (int bj = 0; bj < 8; bj++)
            ub[bj] = *(const float4*)&us[(bj * 8 + tb) * 36 + k4 * 4];
        #pragma unroll
        for (int bj = 0; bj < 8; bj++)
            #pragma unroll
            for (int j = 0; j < 4; j++)
                acc[bj][j] += dot4f(ub[bj], wv[j]);
    }

    #pragma unroll
    for (int bj = 0; bj < 8; bj++) {
        int b = bj * 8 + tb;
        unsigned int lo = (unsigned int)f2bf(acc[bj][0]) | ((unsigned int)f2bf(acc[bj][1]) << 16);
        unsigned int hi = (unsigned int)f2bf(acc[bj][2]) | ((unsigned int)f2bf(acc[bj][3]) << 16);
        uint2 o = {lo, hi};
        *(uint2*)&uhb[(size_t)(b * 1344 + r) * 640 + cdt * 128 + tcd * 4] = o;
    }
}

// ============ K_route: bf16 uhat, 8 r per wave, grid (42, 64) ============
template<int UNIFORM>
__global__ void k_route(const unsigned short* __restrict__ uhb, const float* __restrict__ vsum,
                        float* __restrict__ sout) {
    __shared__ float sl[2560];
    int t = threadIdx.x, wid = t >> 6, lane = t & 63;
    int b = blockIdx.y, rt = blockIdx.x;
    bool act = lane < 40;
    int c = act ? lane : 0;
    float4 vs0 = {0,0,0,0}, vs1 = vs0, vs2 = vs0, vs3 = vs0;
    if (UNIFORM == 0 && act) {
        const float4* vp = (const float4*)&vsum[b * 640 + c * 16];
        vs0 = vp[0]; vs1 = vp[1]; vs2 = vp[2]; vs3 = vp[3];
    }
    float4 ac0 = {0,0,0,0}, ac1 = ac0, ac2 = ac0, ac3 = ac0;
    for (int i = 0; i < 8; i++) {
        int r = rt * 32 + wid * 8 + i;
        const uint4* u4 = (const uint4*)&uhb[((size_t)(b * 1344 + r) * 40 + c) * 16];
        float4 a0 = {0,0,0,0}, a1 = a0, a2 = a0, a3 = a0;
        if (act) {
            uint4 q0 = u4[0], q1 = u4[1];
            a0.x = bfl(q0.x); a0.y = bfh(q0.x); a0.z = bfl(q0.y); a0.w = bfh(q0.y);
            a1.x = bfl(q0.z); a1.y = bfh(q0.z); a1.z = bfl(q0.w); a1.w = bfh(q0.w);
            a2.x = bfl(q1.x); a2.y = bfh(q1.x); a2.z = bfl(q1.y); a2.w = bfh(q1.y);
            a3.x = bfl(q1.z); a3.y = bfh(q1.z); a3.z = bfl(q1.w); a3.w = bfh(q1.w);
        }
        float w;
        if (UNIFORM) {
            w = 0.025f;
        } else {
            float dt = act ? (dot4f(a0, vs0) + dot4f(a1, vs1) + dot4f(a2, vs2) + dot4f(a3, vs3))
                           : -1e30f;
            float mx = dt;
            #pragma unroll
            for (int m2 = 32; m2 >= 1; m2 >>= 1) mx = fmaxf(mx, __shfl_xor(mx, m2));
            float e = act ? __expf(dt - mx) : 0.f;
            float se = e;
            #pragma unroll
            for (int m2 = 32; m2 >= 1; m2 >>= 1) se += __shfl_xor(se, m2);
            w = e / se;
        }
        ac0.x += w * a0.x; ac0.y += w * a0.y; ac0.z += w * a0.z; ac0.w += w * a0.w;
        ac1.x += w * a1.x; ac1.y += w * a1.y; ac1.z += w * a1.z; ac1.w += w * a1.w;
        ac2.x += w * a2.x; ac2.y += w * a2.y; ac2.z += w * a2.z; ac2.w += w * a2.w;
        ac3.x += w * a3.x; ac3.y += w * a3.y; ac3.z += w * a3.z; ac3.w += w * a3.w;
    }
    if (act) {
        float4* sp = (float4*)&sl[wid * 640 + c * 16];
        sp[0] = ac0; sp[1] = ac1; sp[2] = ac2; sp[3] = ac3;
    }
    __syncthreads();
    for (int jj = t; jj < 640; jj += 256)
        atomicAdd(&sout[b * 640 + jj], sl[jj] + sl[640 + jj] + sl[1280 + jj] + sl[1920 + jj]);
}

// ============ K8: squash s -> v ============
__global__ void k8(const float* __restrict__ sin, float* __restrict__ vout,
                   float* __restrict__ vsum, int addsum) {
    int t = threadIdx.x;
    int row = blockIdx.x * 16 + (t >> 4);
    int d = t & 15;
    float v = sin[row * 16 + d];
    float sq = v * v;
    #pragma unroll
    for (int m = 8; m >= 1; m >>= 1) sq += __shfl_xor(sq, m, 16);
    float scale = (sq / (1.f + sq)) / (sqrtf(sq) + 1e-8f);
    float o = v * scale;
    vout[row * 16 + d] = o;
    if (addsum) vsum[row * 16 + d] += o;
}

// ============ K10: head (512 thr) ============
__global__ void k10_head(const float* __restrict__ v,
                         const float* __restrict__ cw1, const float* __restrict__ cb1,
                         const float* __restrict__ cw2, const float* __restrict__ cb2,
                         const float* __restrict__ dw1, const float* __restrict__ db1,
                         const float* __restrict__ dw2, const float* __restrict__ db2,
                         float* __restrict__ out) {
    __shared__ float flat[640], hidp[512], hid[256], hd[256], lgs[40];
    __shared__ float smx, ssum;
    __shared__ int chat;
    int t = threadIdx.x, b = blockIdx.x;
    for (int j = t; j < 640; j += 512) flat[j] = v[b * 640 + j];
    __syncthreads();
    int h = t & 255, half = t >> 8;
    {
        float a = 0.f;
        int j0 = half * 320;
        for (int j = j0; j < j0 + 320; j++) a += flat[j] * cw1[h * 640 + j];
        hidp[t] = a;
    }
    __syncthreads();
    if (t < 256) hid[t] = fmaxf(hidp[t] + hidp[t + 256] + cb1[t], 0.f);
    __syncthreads();
    if (t < 320) {
        int c = t >> 3, s = t & 7;
        float p = 0.f;
        int h0 = s * 32;
        for (int h2 = h0; h2 < h0 + 32; h2++) p += hid[h2] * cw2[c * 256 + h2];
        p += __shfl_xor(p, 1); p += __shfl_xor(p, 2); p += __shfl_xor(p, 4);
        if (s == 0) lgs[c] = p + cb2[c];
    }
    __syncthreads();
    if (t == 0) {
        float mx = lgs[0]; int am = 0;
        for (int c2 = 1; c2 < 40; c2++) if (lgs[c2] > mx) { mx = lgs[c2]; am = c2; }
        float se = 0.f;
        for (int c2 = 0; c2 < 40; c2++) se += __expf(lgs[c2] - mx);
        smx = mx; ssum = se; chat = am;
    }
    __syncthreads();
    if (t < 40) out[98304 + b * 40 + t] = __expf(lgs[t] - smx) / ssum;
    int cb = chat * 16;
    if (t < 256) {
        float ad = db1[t];
        for (int j = 0; j < 16; j++) ad += flat[cb + j] * dw1[t * 640 + cb + j];
        hd[t] = fmaxf(ad, 0.f);
    }
    __syncthreads();
    for (int o = t; o < 1536; o += 512) {
        float z = db2[o];
        for (int h2 = 0; h2 < 256; h2++) z += hd[h2] * dw2[o * 256 + h2];
        out[b * 1536 + o] = 1.f / (1.f + __expf(-z));
    }
}

extern "C" void kernel_launch(void* const* d_in, const int* in_sizes, int n_in,
                              void* d_out, int out_size, void* d_ws, size_t ws_size,
                              hipStream_t stream) {
    const float* x   = (const float*)d_in[0];
    const float* c1w = (const float*)d_in[1];
    const float* c1b = (const float*)d_in[2];
    const float* g1  = (const float*)d_in[3];
    const float* be1 = (const float*)d_in[4];
    const float* pw  = (const float*)d_in[5];
    const float* pb  = (const float*)d_in[6];
    const float* g2  = (const float*)d_in[7];
    const float* be2 = (const float*)d_in[8];
    const float* Wc  = (const float*)d_in[9];
    const float* cw1 = (const float*)d_in[10];
    const float* cb1 = (const float*)d_in[11];
    const float* cw2 = (const float*)d_in[12];
    const float* cb2 = (const float*)d_in[13];
    const float* dw1 = (const float*)d_in[14];
    const float* db1 = (const float*)d_in[15];
    const float* dw2 = (const float*)d_in[16];
    const float* db2 = (const float*)d_in[17];

    if (ws_size < WS_FLOATS_NEEDED * 4ull) return;

    float* ws  = (float*)d_ws;
    float* out = (float*)d_out;
    float* usq  = ws + O_USQ;
    unsigned short* uhb = (unsigned short*)(ws + O_UHAT);
    float* hpre = ws + O_H;
    float* part = ws + O_PART;
    float* up   = ws + O_UP;
    float* sum1 = ws + O_STATS;
    float* ss1  = sum1 + 256;
    float* sum2 = ss1 + 256;
    float* ss2  = sum2 + 32;
    float* a1  = ws + O_A1;
    float* b1s = ws + O_B1S;
    float* a2  = ws + O_A2;
    float* b2s = ws + O_B2S;
    float* s0   = ws + O_S;
    float* s1   = s0 + 40960;
    float* s2   = s1 + 40960;
    float* vsum = s2 + 40960;
    float* vbuf = ws + O_V;

    hipMemsetAsync(sum1, 0, 576 * sizeof(float), stream);
    hipMemsetAsync(s0, 0, 163840 * sizeof(float), stream);

    k1_conv1<<<dim3(4, 64, 4), 256, 0, stream>>>(x, c1w, c1b, hpre);
    k2a<<<60, 256, 0, stream>>>(hpre, sum1, ss1);
    k2b<<<1, 256, 0, stream>>>(sum1, ss1, g1, be1, a1, b1s);
    k3_conv2<<<dim3(6, 16, 8), 256, 0, stream>>>(hpre, a1, b1s, pw, part);
    k4r<<<112, 256, 0, stream>>>(part, pb, up, sum2, ss2);
    k4b<<<1, 64, 0, stream>>>(sum2, ss2, g2, be2, a2, b2s);
    k5<<<10752, 256, 0, stream>>>(up, a2, b2s, usq);
    k6_uhat<<<dim3(5, 1344), 256, 0, stream>>>(usq, Wc, uhb);
    k_route<1><<<dim3(42, 64), 256, 0, stream>>>(uhb, nullptr, s0);
    k8<<<160, 256, 0, stream>>>(s0, vbuf, vsum, 1);
    k_route<0><<<dim3(42, 64), 256, 0, stream>>>(uhb, vsum, s1);
    k8<<<160, 256, 0, stream>>>(s1, vbuf, vsum, 1);
    k_route<0><<<dim3(42, 64), 256, 0, stream>>>(uhb, vsum, s2);
    k8<<<160, 256, 0, stream>>>(s2, vbuf, vsum, 0);
    k10_head<<<64, 512, 0, stream>>>(vbuf, cw1, cb1, cw2, cb2, dw1, db1, dw2, db2, out);
}